// Round 5
// baseline (238.772 us; speedup 1.0000x reference)
//
#include <hip/hip_runtime.h>
#include <hip/hip_cooperative_groups.h>

namespace cg = cooperative_groups;

#define EPS 1e-5f
constexpr int B = 4, C = 64, H = 128, W = 256;
constexpr int Hg = 512, Wg = 1024;
constexpr int NC = 19;
constexpr int HW = H * W;      // 32768 pixels per (b,c) plane
constexpr int HW4 = HW / 4;    // 8192 packed-class dwords per batch

// Single cooperative kernel, 512 blocks x 256 threads (2 blocks/CU co-resident).
// Phase A: blocks 0..127 downsample+pack gt, per-block histogram.
// Phase B: all blocks accumulate per-class sum/sumsq for a half (b,c)-plane in
//          REGISTERS (19 acc pairs, unrolled compare+select; no LDS in hot loop —
//          round-3 lesson: ds_add_f32 throughput is terrible), butterfly-reduce,
//          store 19 float2 partials per wave. 4 blocks also fold the histograms.
// Phase C: threads 0..18 redo the tiny per-(cid,c) param math; all threads apply
//          out = fma(x, scale[cls], shift[cls]) to the SAME half-plane (L2/L3-hot).
__global__ __launch_bounds__(256, 2) void k_fused(const float* __restrict__ x,
                                                  const int* __restrict__ gt,
                                                  const float* __restrict__ eps_mu,
                                                  const float* __restrict__ eps_std,
                                                  float* __restrict__ out,
                                                  unsigned int* __restrict__ gt_p,
                                                  int* __restrict__ counts_pb, // [NC][128]
                                                  int* __restrict__ counts,    // [B*NC]
                                                  float2* __restrict__ par) {  // [19*B*C][8]
  cg::grid_group grid = cg::this_grid();
  __shared__ int hist[NC];
  __shared__ float2 tab[NC];
  int t = threadIdx.x;
  int blk = blockIdx.x;
  int plane = blk >> 1;            // b*C + c
  int half = blk & 1;
  int b = plane >> 6, c = plane & 63;
  int lane = t & 63, w = t >> 6;

  // ---------------- Phase A: pack gt (blocks 0..127) -------------------------------
  if (blk < 128) {
    if (t < NC) hist[t] = 0;
    __syncthreads();
    int R = blk * 4 + w;                     // row in [0,512) = b*H + h
    int bb = R >> 7, h = R & 127;
    const int* row = gt + (size_t)(bb * Hg + h * 4) * Wg;
    unsigned int c0 = (unsigned int)row[lane * 16 + 0];
    unsigned int c1 = (unsigned int)row[lane * 16 + 4];
    unsigned int c2 = (unsigned int)row[lane * 16 + 8];
    unsigned int c3 = (unsigned int)row[lane * 16 + 12];
    gt_p[R * 64 + lane] = c0 | (c1 << 8) | (c2 << 16) | (c3 << 24);
    atomicAdd(&hist[c0], 1); atomicAdd(&hist[c1], 1);   // classes in [0,19)
    atomicAdd(&hist[c2], 1); atomicAdd(&hist[c3], 1);
    __syncthreads();
    if (t < NC) counts_pb[t * 128 + blk] = hist[t];
  }
  grid.sync();

  // ---------------- Phase B: per-class sum/sumsq, half-plane ------------------------
  if (c == 0 && half == 0 && t < NC) {       // 4 blocks fold hists -> counts[b][cls]
    const int4* cp = (const int4*)&counts_pb[t * 128 + b * 32];
    int s = 0;
#pragma unroll
    for (int j = 0; j < 8; j++) { int4 cv = cp[j]; s += cv.x + cv.y + cv.z + cv.w; }
    counts[b * NC + t] = s;
  }

  float accS[NC], accQ[NC];
#pragma unroll
  for (int k = 0; k < NC; k++) { accS[k] = 0.f; accQ[k] = 0.f; }

  const float4* xp = (const float4*)x + (size_t)plane * (HW / 4) + half * 4096;
  const unsigned int* gp = gt_p + (size_t)b * HW4 + half * 4096;
  for (int j = 0; j < 16; j++) {
    int i = j * 256 + t;
    float4 v = xp[i];
    unsigned int g = gp[i];
    int c0 = g & 255, c1 = (g >> 8) & 255, c2 = (g >> 16) & 255, c3 = g >> 24;
#pragma unroll
    for (int k = 0; k < NC; k++) {
      float m0 = (c0 == k) ? v.x : 0.f;
      float m1 = (c1 == k) ? v.y : 0.f;
      float m2 = (c2 == k) ? v.z : 0.f;
      float m3 = (c3 == k) ? v.w : 0.f;
      accS[k] += (m0 + m1) + (m2 + m3);
      accQ[k] += fmaf(m0, m0, fmaf(m1, m1, fmaf(m2, m2, m3 * m3)));
    }
  }
#pragma unroll
  for (int k = 0; k < NC; k++) {             // 64-lane butterfly
    float s = accS[k], qq = accQ[k];
    for (int m = 32; m >= 1; m >>= 1) {
      s  += __shfl_xor(s, m, 64);
      qq += __shfl_xor(qq, m, 64);
    }
    accS[k] = s; accQ[k] = qq;
  }
  if (lane == 0) {
#pragma unroll
    for (int k = 0; k < NC; k++) {
      int e = (k * B + b) * C + c;
      par[e * 8 + half * 4 + w] = make_float2(accS[k], accQ[k]);
    }
  }
  grid.sync();

  // ---------------- Phase C: params (threads 0..18) + apply -------------------------
  float4* op = (float4*)out + (size_t)plane * (HW / 4) + half * 4096;
  float4 v0 = xp[t];                         // prefetch tile 0 during param math
  unsigned int g0 = gp[t];

  if (t < NC) {
    float mean[B], stdv[B];
    float msum = 0.f, ssum = 0.f;
#pragma unroll
    for (int bb = 0; bb < B; bb++) {
      int cnt = counts[bb * NC + t];
      float n = cnt > 0 ? (float)cnt : 1.f;  // npx = where(npx==0, 1, npx)
      const float4* pp = (const float4*)&par[((t * B + bb) * C + c) * 8];
      float s = 0.f, qq = 0.f;
#pragma unroll
      for (int j = 0; j < 4; j++) { float4 p = pp[j]; s += p.x + p.z; qq += p.y + p.w; }
      float m = s / n;
      float var = qq / n - m * m;            // biased (divide by npx), as reference
      var = var > 0.f ? var : 0.f;
      mean[bb] = m;
      stdv[bb] = sqrtf(var + EPS);
      msum += m; ssum += stdv[bb];
    }
    float mbar = msum * 0.25f, sbar = ssum * 0.25f;
    float vm = 0.f, vs = 0.f;
#pragma unroll
    for (int bb = 0; bb < B; bb++) {
      float dm = mean[bb] - mbar; vm += dm * dm;
      float ds = stdv[bb] - sbar; vs += ds * ds;
    }
    float sqvm = sqrtf(vm * (1.f / 3.f) + EPS);   // ddof=1 over B=4
    float sqvs = sqrtf(vs * (1.f / 3.f) + EPS);
    int e = (t * B + b) * C + c;
    float beta  = mean[b] + eps_mu[e]  * sqvm;
    float gamma = stdv[b] + eps_std[e] * sqvs;
    float sc = gamma / stdv[b];
    tab[t] = make_float2(sc, beta - mean[b] * sc);  // out = x*sc + shift
  }
  __syncthreads();

  {
    float2 a0 = tab[g0 & 255], a1 = tab[(g0 >> 8) & 255];
    float2 a2 = tab[(g0 >> 16) & 255], a3 = tab[g0 >> 24];
    float4 o;
    o.x = fmaf(v0.x, a0.x, a0.y);
    o.y = fmaf(v0.y, a1.x, a1.y);
    o.z = fmaf(v0.z, a2.x, a2.y);
    o.w = fmaf(v0.w, a3.x, a3.y);
    op[t] = o;
  }
  for (int j = 1; j < 16; j++) {
    int i = j * 256 + t;
    float4 v = xp[i];
    unsigned int g = gp[i];
    float2 a0 = tab[g & 255], a1 = tab[(g >> 8) & 255];
    float2 a2 = tab[(g >> 16) & 255], a3 = tab[g >> 24];
    float4 o;
    o.x = fmaf(v.x, a0.x, a0.y);
    o.y = fmaf(v.y, a1.x, a1.y);
    o.z = fmaf(v.z, a2.x, a2.y);
    o.w = fmaf(v.w, a3.x, a3.y);
    op[i] = o;
  }
}

extern "C" void kernel_launch(void* const* d_in, const int* in_sizes, int n_in,
                              void* d_out, int out_size, void* d_ws, size_t ws_size,
                              hipStream_t stream) {
  const float* x       = (const float*)d_in[0];
  const int*   gt      = (const int*)  d_in[1];
  const float* eps_mu  = (const float*)d_in[2];
  const float* eps_std = (const float*)d_in[3];
  float* out = (float*)d_out;

  // workspace layout (~453 KB, fully overwritten every call)
  char* ws = (char*)d_ws;
  unsigned int* gt_p     = (unsigned int*)(ws);           // 131072 B packed classes
  int*          counts_pb= (int*)   (ws + 131072);        // 19*128*4 = 9728 B
  int*          counts   = (int*)   (ws + 140800);        // 304 B
  float2*       par      = (float2*)(ws + 141104);        // 19*B*C*8*8 = 311296 B

  void* args[] = { (void*)&x, (void*)&gt, (void*)&eps_mu, (void*)&eps_std,
                   (void*)&out, (void*)&gt_p, (void*)&counts_pb, (void*)&counts,
                   (void*)&par };
  hipLaunchCooperativeKernel((const void*)k_fused, dim3(512), dim3(256),
                             args, 0, stream);
}

// Round 7
// 101.369 us; speedup vs baseline: 2.3555x; 2.3555x over previous
//
#include <hip/hip_runtime.h>

#define EPS 1e-5f
constexpr int B = 4, C = 64, H = 128, W = 256;
constexpr int Hg = 512, Wg = 1024;
constexpr int NC = 19;
constexpr int HW = H * W;      // 32768 pixels per (b,c) plane
constexpr int HW4 = HW / 4;    // 8192 packed-class dwords per batch

typedef float f32x4 __attribute__((ext_vector_type(4)));  // native vec for nt-store

// ---------------- K1: downsample gt (stride 4), pack classes to u8, histogram -------
// 128 blocks x 256 threads; block = 4 rows of one batch. Per-block hist ->
// counts_pb[cid][128] (transposed, int4-friendly for the k_stats fold).
__global__ __launch_bounds__(256) void k_pack(const int* __restrict__ gt,
                                              unsigned int* __restrict__ gt_p,
                                              int* __restrict__ counts_pb) { // [NC][128]
  __shared__ int hist[NC];
  int t = threadIdx.x;
  if (t < NC) hist[t] = 0;
  __syncthreads();
  int R = blockIdx.x * 4 + (t >> 6);        // global row in [0,512) = b*H + h
  int ws = t & 63;                          // 4-pixel segment within the row
  int b = R >> 7, h = R & 127;
  const int* row = gt + (size_t)(b * Hg + h * 4) * Wg;
  unsigned int c0 = (unsigned int)row[ws * 16 + 0];
  unsigned int c1 = (unsigned int)row[ws * 16 + 4];
  unsigned int c2 = (unsigned int)row[ws * 16 + 8];
  unsigned int c3 = (unsigned int)row[ws * 16 + 12];
  gt_p[R * 64 + ws] = c0 | (c1 << 8) | (c2 << 16) | (c3 << 24);
  atomicAdd(&hist[c0], 1); atomicAdd(&hist[c1], 1);   // classes in [0,19)
  atomicAdd(&hist[c2], 1); atomicAdd(&hist[c3], 1);
  __syncthreads();
  if (t < NC) counts_pb[t * 128 + blockIdx.x] = hist[t];
}

// ---------------- K2: per-(b,c,quarter) partial per-class sum/sumsq -----------------
// R2-measured-best scheme: float2 LDS accumulators acc[cls*256+t] (bank = f(t) only
// -> conflict-free b64 RMW; aliasing chains hidden by 16 waves/CU). LDS-BW-bound
// ~268 MB @ 69 TB/s ~ 4 us. NO ds atomics (R3: terrible), NO register/compare-select
// (R4: VALU floor 8.7 us + shuffle tax measured slower than this).
__global__ __launch_bounds__(256) void k_stats(const float* __restrict__ x,
                                               const unsigned int* __restrict__ gt_p,
                                               const int* __restrict__ counts_pb,
                                               float2* __restrict__ par,   // [19*B*C][4]
                                               int* __restrict__ counts) { // [B*NC]
  __shared__ float2 acc[NC * 256];   // 38912 B -> 4 blocks/CU
  int t = threadIdx.x;
  for (int k = t; k < NC * 256; k += 256) acc[k] = make_float2(0.f, 0.f);
  int plane = blockIdx.x >> 2;       // b*C + c
  int q = blockIdx.x & 3;
  int b = plane >> 6, c = plane & 63;

  // 4 designated blocks fold k_pack's per-block hists -> counts[b][cls]
  if (c == 0 && q == 0 && t < NC) {
    const int4* cp = (const int4*)&counts_pb[t * 128 + b * 32];
    int s = 0;
#pragma unroll
    for (int j = 0; j < 8; j++) { int4 cv = cp[j]; s += cv.x + cv.y + cv.z + cv.w; }
    counts[b * NC + t] = s;
  }
  __syncthreads();

  const float4* xp = (const float4*)x + (size_t)plane * (HW / 4) + q * 2048;
  const unsigned int* gp = gt_p + (size_t)b * HW4 + q * 2048;
  for (int j = 0; j < 8; j++) {
    int i = j * 256 + t;
    float4 v = xp[i];
    unsigned int g = gp[i];
    int c0 = g & 255, c1 = (g >> 8) & 255, c2 = (g >> 16) & 255, c3 = g >> 24;
    float2 a;
    a = acc[c0 * 256 + t]; a.x += v.x; a.y += v.x * v.x; acc[c0 * 256 + t] = a;
    a = acc[c1 * 256 + t]; a.x += v.y; a.y += v.y * v.y; acc[c1 * 256 + t] = a;
    a = acc[c2 * 256 + t]; a.x += v.z; a.y += v.z * v.z; acc[c2 * 256 + t] = a;
    a = acc[c3 * 256 + t]; a.x += v.w; a.y += v.w * v.w; acc[c3 * 256 + t] = a;
  }
  __syncthreads();

  // One-barrier reduction: wave w owns classes w, w+4, ... ; 4 LDS reads + butterfly.
  int w = t >> 6, lane = t & 63;
  for (int k = w; k < NC; k += 4) {
    float2 a0 = acc[k * 256 + lane];
    float2 a1 = acc[k * 256 + 64 + lane];
    float2 a2 = acc[k * 256 + 128 + lane];
    float2 a3 = acc[k * 256 + 192 + lane];
    float s  = a0.x + a1.x + a2.x + a3.x;
    float qq = a0.y + a1.y + a2.y + a3.y;
    for (int m = 32; m >= 1; m >>= 1) {
      s  += __shfl_xor(s, m, 64);
      qq += __shfl_xor(qq, m, 64);
    }
    if (lane == 0) {
      int e = (k * B + b) * C + c;
      par[e * 4 + q] = make_float2(s, qq);
    }
  }
}

// ---------------- K3: fused params (threads 0..18) + apply --------------------------
__global__ __launch_bounds__(256) void k_apply(const float* __restrict__ x,
                                               const unsigned int* __restrict__ gt_p,
                                               const float2* __restrict__ par,
                                               const int* __restrict__ counts,
                                               const float* __restrict__ eps_mu,
                                               const float* __restrict__ eps_std,
                                               float* __restrict__ out) {
  __shared__ float2 tab[NC];
  int t = threadIdx.x;
  int plane = blockIdx.x >> 2;     // b*C + c
  int q = blockIdx.x & 3;
  int b = plane >> 6, c = plane & 63;
  const float4* xp = (const float4*)x + (size_t)plane * (HW / 4) + q * 2048;
  const unsigned int* gp = gt_p + (size_t)b * HW4 + q * 2048;
  f32x4* op = (f32x4*)((float4*)out + (size_t)plane * (HW / 4) + q * 2048);

  // prefetch tile j=0 while params compute
  float4 v0 = xp[t];
  unsigned int g0 = gp[t];

  if (t < NC) {                    // redundant tiny per-(cid,c) param math
    float mean[B], stdv[B];
    float msum = 0.f, ssum = 0.f;
#pragma unroll
    for (int bb = 0; bb < B; bb++) {
      int cnt = counts[bb * NC + t];
      float n = cnt > 0 ? (float)cnt : 1.f;   // npx = where(npx==0, 1, npx)
      const float4* pp = (const float4*)&par[((t * B + bb) * C + c) * 4];
      float4 p0 = pp[0], p1 = pp[1];
      float s  = (p0.x + p0.z) + (p1.x + p1.z);
      float qq = (p0.y + p0.w) + (p1.y + p1.w);
      float m = s / n;
      float var = qq / n - m * m;             // biased (divide by npx), as reference
      var = var > 0.f ? var : 0.f;
      mean[bb] = m;
      stdv[bb] = sqrtf(var + EPS);
      msum += m; ssum += stdv[bb];
    }
    float mbar = msum * 0.25f, sbar = ssum * 0.25f;
    float vm = 0.f, vs = 0.f;
#pragma unroll
    for (int bb = 0; bb < B; bb++) {
      float dm = mean[bb] - mbar; vm += dm * dm;
      float ds = stdv[bb] - sbar; vs += ds * ds;
    }
    float sqvm = sqrtf(vm * (1.f / 3.f) + EPS);   // ddof=1 over B=4
    float sqvs = sqrtf(vs * (1.f / 3.f) + EPS);
    int e = (t * B + b) * C + c;
    float beta  = mean[b] + eps_mu[e]  * sqvm;
    float gamma = stdv[b] + eps_std[e] * sqvs;
    float sc = gamma / stdv[b];
    tab[t] = make_float2(sc, beta - mean[b] * sc);  // out = x*sc + shift
  }
  __syncthreads();

  {
    float2 a0 = tab[g0 & 255], a1 = tab[(g0 >> 8) & 255];
    float2 a2 = tab[(g0 >> 16) & 255], a3 = tab[g0 >> 24];
    f32x4 o;
    o.x = fmaf(v0.x, a0.x, a0.y);
    o.y = fmaf(v0.y, a1.x, a1.y);
    o.z = fmaf(v0.z, a2.x, a2.y);
    o.w = fmaf(v0.w, a3.x, a3.y);
    __builtin_nontemporal_store(o, &op[t]);   // streaming: don't evict L2-hot x/gt_p
  }
  for (int j = 1; j < 8; j++) {
    int i = j * 256 + t;
    float4 v = xp[i];
    unsigned int g = gp[i];
    float2 a0 = tab[g & 255], a1 = tab[(g >> 8) & 255];
    float2 a2 = tab[(g >> 16) & 255], a3 = tab[g >> 24];
    f32x4 o;
    o.x = fmaf(v.x, a0.x, a0.y);
    o.y = fmaf(v.y, a1.x, a1.y);
    o.z = fmaf(v.z, a2.x, a2.y);
    o.w = fmaf(v.w, a3.x, a3.y);
    __builtin_nontemporal_store(o, &op[i]);
  }
}

extern "C" void kernel_launch(void* const* d_in, const int* in_sizes, int n_in,
                              void* d_out, int out_size, void* d_ws, size_t ws_size,
                              hipStream_t stream) {
  const float* x       = (const float*)d_in[0];
  const int*   gt      = (const int*)  d_in[1];
  const float* eps_mu  = (const float*)d_in[2];
  const float* eps_std = (const float*)d_in[3];
  float* out = (float*)d_out;

  // workspace layout (~297 KB, fully overwritten every call)
  char* ws = (char*)d_ws;
  unsigned int* gt_p     = (unsigned int*)(ws);           // 131072 B packed classes
  int*          counts_pb= (int*)   (ws + 131072);        // 19*128*4 = 9728 B
  int*          counts   = (int*)   (ws + 140800);        // 304 B (padded)
  float2*       par      = (float2*)(ws + 141104);        // 19*B*C*4*8 = 155648 B

  hipLaunchKernelGGL(k_pack,  dim3(B * H / 4), dim3(256), 0, stream, gt, gt_p, counts_pb);
  hipLaunchKernelGGL(k_stats, dim3(B * C * 4), dim3(256), 0, stream,
                     x, gt_p, counts_pb, par, counts);
  hipLaunchKernelGGL(k_apply, dim3(B * C * 4), dim3(256), 0, stream,
                     x, gt_p, par, counts, eps_mu, eps_std, out);
}